// Round 7
// baseline (921.773 us; speedup 1.0000x reference)
//
#include <hip/hip_runtime.h>

typedef __bf16 bf16;
typedef __attribute__((ext_vector_type(8))) __bf16 bf16x8;
typedef __attribute__((ext_vector_type(4))) __bf16 bf16x4;
typedef __attribute__((ext_vector_type(2))) __bf16 bf16x2;
typedef __attribute__((ext_vector_type(4))) float f32x4;
typedef __attribute__((ext_vector_type(4))) unsigned int u32x4;

#define TOKENS 3136
#define CC 768
#define S196 196
#define M_ROWS 25088   // 16*8*196
#define BATCH 16

__device__ __forceinline__ float bf2f(bf16 x) { return (float)x; }
__device__ __forceinline__ bf16 f2bf(float x) { return (bf16)x; }

__device__ __forceinline__ float gelu_exact(float x) {
    return 0.5f * x * (1.0f + erff(x * 0.70710678118654752f));
}

__device__ __forceinline__ unsigned int packbf(float a, float b) {
    bf16x2 v; v[0] = (bf16)a; v[1] = (bf16)b;
    return __builtin_bit_cast(unsigned int, v);
}

// async global->LDS, 16B per lane; LDS dest = wave-uniform base + lane*16
#define GLOAD_LDS16(gp, lp) \
    __builtin_amdgcn_global_load_lds((const __attribute__((address_space(1))) void*)(gp), \
                                     (__attribute__((address_space(3))) void*)(lp), 16, 0, 0)

// ---------------------------------------------------------------------------
// All weight transposes in ONE dispatch. z selects the weight.
// Wt[n][k] = W[k][n], fp32 -> bf16. All K=768.
// ---------------------------------------------------------------------------
__global__ __launch_bounds__(256)
void transpose_all(const float* W0, const float* W1, const float* W2,
                   const float* W3, const float* W4, const float* W5,
                   bf16* D0, bf16* D1, bf16* D2, bf16* D3, bf16* D4, bf16* D5)
{
    const float* Ws[6] = {W0, W1, W2, W3, W4, W5};
    bf16*        Ds[6] = {D0, D1, D2, D3, D4, D5};
    const int    Ns[6] = {768, 1536, 768, 1536, 768, 768};
    int z = blockIdx.z;
    int N = Ns[z];
    int n0 = blockIdx.y * 32;
    if (n0 >= N) return;
    const float* W = Ws[z];
    bf16* Wt = Ds[z];
    const int K = 768;
    __shared__ float tle[32][33];
    int k0 = blockIdx.x * 32;
    int tx = threadIdx.x & 31, ty = threadIdx.x >> 5;   // 8 rows of 32
    for (int r = ty; r < 32; r += 8)
        tle[r][tx] = W[(long)(k0 + r) * N + n0 + tx];
    __syncthreads();
    for (int r = ty; r < 32; r += 8)
        Wt[(long)(n0 + r) * K + k0 + tx] = f2bf(tle[tx][r]);
}

// ---------------------------------------------------------------------------
// Bias convert (fp32 -> bf16) into packed ws array.
// Layout: [bq_d(768) | bkv_a(1536) | bq_a(768) | bkv_d(1536) | bp_d | bp_a]
// ---------------------------------------------------------------------------
__global__ __launch_bounds__(256)
void conv_bias(const float* b0, const float* b1, const float* b2,
               const float* b3, const float* b4, const float* b5,
               bf16* __restrict__ dst)
{
    const float* srcs[6] = {b0, b1, b2, b3, b4, b5};
    const int sizes[6]   = {768, 1536, 768, 1536, 768, 768};
    const int offs[6]    = {0, 768, 2304, 3072, 4608, 5376};
    int which = blockIdx.x;
    const float* s = srcs[which];
    int n = sizes[which];
    bf16* d = dst + offs[which];
    for (int i = threadIdx.x; i < n; i += 256)
        d[i] = f2bf(s[i]);
}

// ---------------------------------------------------------------------------
// Reorder x_in (b, nt, nh, nw, t, c) fp32 -> bf16 x_a / x_d rows
// ---------------------------------------------------------------------------
__global__ __launch_bounds__(256)
void reorder_split(const float* __restrict__ x_in, bf16* __restrict__ xa,
                   bf16* __restrict__ xd)
{
    long idx = (long)blockIdx.x * 256 + threadIdx.x;
    const long total = (long)BATCH * 16 * S196 * 96;
    if (idx >= total) return;
    int  c8  = (int)(idx % 96) * 8;
    long row = idx / 96;
    int  s   = (int)(row % S196);
    long r2  = row / S196;
    int  tt  = (int)(r2 & 15);
    int  b   = (int)(r2 >> 4);
    int  nt  = tt >> 2, t = tt & 3;
    int  nh  = s / 14,  nw = s % 14;
    long src  = ((long)b * TOKENS + ((nt * 14 + nh) * 14 + nw) * 4 + t) * CC + c8;
    bf16* dst = (tt & 1) ? xd : xa;
    long doff = ((long)(b * 8 + (tt >> 1)) * S196 + s) * CC + c8;
    const float* sp = x_in + src;
    f32x4 a = *(const f32x4*)sp;
    f32x4 c = *(const f32x4*)(sp + 4);
    bf16x8 v;
    v[0] = f2bf(a[0]); v[1] = f2bf(a[1]); v[2] = f2bf(a[2]); v[3] = f2bf(a[3]);
    v[4] = f2bf(c[0]); v[5] = f2bf(c[1]); v[6] = f2bf(c[2]); v[7] = f2bf(c[3]);
    *(bf16x8*)(dst + doff) = v;
}

// ---------------------------------------------------------------------------
// Row-sum helpers + pooled outputs
// ---------------------------------------------------------------------------
__device__ __forceinline__ float row_sum768(const bf16* __restrict__ p, int lane)
{
    float s = 0.f;
    bf16x8 v = *(const bf16x8*)(p + lane * 8);
    #pragma unroll
    for (int j = 0; j < 8; ++j) s += bf2f(v[j]);
    if (lane < 32) {
        bf16x8 w = *(const bf16x8*)(p + 512 + lane * 8);
        #pragma unroll
        for (int j = 0; j < 8; ++j) s += bf2f(w[j]);
    }
    #pragma unroll
    for (int off = 32; off; off >>= 1) s += __shfl_xor(s, off, 64);
    return s;
}

__global__ __launch_bounds__(256)
void pool_ad(const bf16* __restrict__ xa, const bf16* __restrict__ xd,
             float* __restrict__ pool0)
{
    int id = blockIdx.x * 4 + (threadIdx.x >> 6);
    int lane = threadIdx.x & 63;
    float sa = row_sum768(xa + (long)id * CC, lane);
    float sd = row_sum768(xd + (long)id * CC, lane);
    if (lane == 0) pool0[id] = (sa + sd) * (0.5f / 768.0f);
}

__global__ __launch_bounds__(256)
void out_final(const bf16* __restrict__ xa, const bf16* __restrict__ xd,
               const float* __restrict__ pool0, float* __restrict__ out)
{
    int id = blockIdx.x * 4 + (threadIdx.x >> 6);
    int lane = threadIdx.x & 63;
    float sa = row_sum768(xa + (long)id * CC, lane);
    float sd = row_sum768(xd + (long)id * CC, lane);
    if (lane == 0) {
        out[id]          = pool0[id] - sa * (1.0f / 768.0f);
        out[M_ROWS + id] = sd * (1.0f / 768.0f);
    }
}

// ---------------------------------------------------------------------------
// GEMM: C = A(MxK) @ Bt(NxK)^T + bias. 128x256x32 tile, 4 waves (2x2),
// each wave 64x128 (4x8 16x16x32 MFMA): 12 ds_read_b128 : 32 MFMA per iter
// (vs 8:16 at 64x64) -> fewer LDS cycles and barriers per MFMA.
// global_load_lds width=16 staging; GROUP_M=16 L2 swizzle; ldc decoupled.
// EPI: 0 -> C = x ; 1 -> C = res - gelu(x) ; 2 -> C = res + gelu(x)
// ---------------------------------------------------------------------------
template<int EPI>
__global__ __launch_bounds__(256, 2)
void gemm_bt(const bf16* __restrict__ A, const bf16* __restrict__ Bt,
             const bf16* __restrict__ bias, const bf16* __restrict__ res,
             bf16* __restrict__ C, int ldc, int K, int mTiles, int nTiles)
{
    constexpr int BM = 128, BN = 256, BK = 32;
    __shared__ alignas(16) bf16 sA[BM * BK];   // 8 KB
    __shared__ alignas(16) bf16 sB[BN * BK];   // 16 KB
    const int tid  = threadIdx.x;
    const int lane = tid & 63, wave = tid >> 6;
    const int wm   = wave >> 1, wn = wave & 1;
    const int quad = lane >> 4, l16 = lane & 15;

    // GROUP_M swizzle
    const int GM = 16;
    int pid   = blockIdx.x;
    int group = GM * nTiles;
    int gid   = pid / group;
    int rem   = pid - gid * group;
    int first = gid * GM;
    int gm    = (mTiles - first < GM) ? (mTiles - first) : GM;
    int bm    = first + rem % gm;
    int bn    = rem / gm;

    const long m0 = (long)bm * BM;
    const long n0 = (long)bn * BN;

    f32x4 acc[4][8] = {};

    for (int kt = 0; kt < K; kt += BK) {
        if (kt) __syncthreads();
        // A: 512 16B chunks; B: 1024 chunks. chunk ci -> r=ci>>2, kc=ci&3.
        #pragma unroll
        for (int c = 0; c < 2; ++c) {
            int ci = (wave * 2 + c) * 64 + lane;
            GLOAD_LDS16(A + (m0 + (ci >> 2)) * K + kt + (ci & 3) * 8,
                        sA + (wave * 2 + c) * 512);
        }
        #pragma unroll
        for (int c = 0; c < 4; ++c) {
            int ci = (wave * 4 + c) * 64 + lane;
            GLOAD_LDS16(Bt + (n0 + (ci >> 2)) * K + kt + (ci & 3) * 8,
                        sB + (wave * 4 + c) * 512);
        }
        __syncthreads();

        bf16x8 af[4], bfr[8];
        #pragma unroll
        for (int mi = 0; mi < 4; ++mi)
            af[mi] = *(const bf16x8*)(sA + (wm * 64 + mi * 16 + l16) * BK + quad * 8);
        #pragma unroll
        for (int ni = 0; ni < 8; ++ni)
            bfr[ni] = *(const bf16x8*)(sB + (wn * 128 + ni * 16 + l16) * BK + quad * 8);
        #pragma unroll
        for (int mi = 0; mi < 4; ++mi)
            #pragma unroll
            for (int ni = 0; ni < 8; ++ni)
                acc[mi][ni] = __builtin_amdgcn_mfma_f32_16x16x32_bf16(af[mi], bfr[ni], acc[mi][ni], 0, 0, 0);
    }

    // Epilogue. D layout: col = lane&15, row = quad*4 + r
    #pragma unroll
    for (int mi = 0; mi < 4; ++mi) {
        #pragma unroll
        for (int ni = 0; ni < 8; ++ni) {
            int mg = (int)m0 + wm * 64 + mi * 16 + quad * 4;
            int ng = (int)n0 + wn * 128 + ni * 16 + l16;
            float bn_ = bf2f(bias[ng]);
            #pragma unroll
            for (int r = 0; r < 4; ++r) {
                float x = acc[mi][ni][r] + bn_;
                long off = (long)(mg + r) * ldc + ng;
                if (EPI == 0)      C[off] = f2bf(x);
                else if (EPI == 1) C[off] = f2bf(bf2f(res[off]) - gelu_exact(x));
                else               C[off] = f2bf(bf2f(res[off]) + gelu_exact(x));
            }
        }
    }
}

// ---------------------------------------------------------------------------
// MFMA attention, stride-parameterized. One block per (head h, instance bj).
// St = K·Q^T, in-register softmax, O^T = V^T·P^T via ds_bpermute fragments.
// ---------------------------------------------------------------------------
#define KSTR 72
#define VSTR 264

__global__ __launch_bounds__(256)
void attn_mfma(const bf16* __restrict__ Q, int ldq,
               const bf16* __restrict__ KV, int ldkv,
               bf16* __restrict__ O)
{
    const int h  = blockIdx.x;   // 12
    const int bj = blockIdx.y;   // 128
    __shared__ alignas(16) bf16 Ks[208 * KSTR];
    __shared__ alignas(16) bf16 Vt[64 * VSTR];
    const int tid = threadIdx.x, lane = tid & 63, wave = tid >> 6;
    const int quad = lane >> 4, l16 = lane & 15;

    const bf16* qg = Q  + (long)bj * S196 * ldq  + h * 64;
    const bf16* kg = KV + (long)bj * S196 * ldkv + h * 64;
    const bf16* vg = kg + CC;

    for (int i = tid; i < 208 * 8; i += 256) {
        int r = i >> 3, c8 = (i & 7) * 8;
        bf16x8 v = {};
        if (r < S196) v = *(const bf16x8*)(kg + (long)r * ldkv + c8);
        *(bf16x8*)(Ks + r * KSTR + c8) = v;
    }
    for (int i = tid; i < 256 * 8; i += 256) {
        int g   = i >> 6;
        int c8  = (g & 7) * 8;
        int tok = (g >> 3) * 64 + (i & 63);
        bf16x8 v = {};
        if (tok < S196) v = *(const bf16x8*)(vg + (long)tok * ldkv + c8);
        #pragma unroll
        for (int j = 0; j < 8; ++j)
            Vt[(c8 + j) * VSTR + tok] = v[j];
    }
    __syncthreads();

    for (int qt = wave; qt < 13; qt += 4) {
        int qrow = qt * 16 + l16; if (qrow > 195) qrow = 195;
        const bf16* qrp = qg + (long)qrow * ldq + quad * 8;
        bf16x8 qf0 = *(const bf16x8*)(qrp);
        bf16x8 qf1 = *(const bf16x8*)(qrp + 32);

        f32x4 st[13];
        #pragma unroll
        for (int rt = 0; rt < 13; ++rt) st[rt] = (f32x4){0.f, 0.f, 0.f, 0.f};
        #pragma unroll
        for (int rt = 0; rt < 13; ++rt) {
            const bf16* kb = Ks + (rt * 16 + l16) * KSTR + quad * 8;
            bf16x8 kf0 = *(const bf16x8*)(kb);
            bf16x8 kf1 = *(const bf16x8*)(kb + 32);
            st[rt] = __builtin_amdgcn_mfma_f32_16x16x32_bf16(kf0, qf0, st[rt], 0, 0, 0);
            st[rt] = __builtin_amdgcn_mfma_f32_16x16x32_bf16(kf1, qf1, st[rt], 0, 0, 0);
        }

        const float SC = 0.125f;
        #pragma unroll
        for (int rt = 0; rt < 13; ++rt) {
            st[rt][0] *= SC; st[rt][1] *= SC; st[rt][2] *= SC; st[rt][3] *= SC;
        }
        if (quad != 0)
            st[12] = (f32x4){-1e30f, -1e30f, -1e30f, -1e30f};

        float m = -1e30f;
        #pragma unroll
        for (int rt = 0; rt < 13; ++rt)
            m = fmaxf(m, fmaxf(fmaxf(st[rt][0], st[rt][1]), fmaxf(st[rt][2], st[rt][3])));
        m = fmaxf(m, __shfl_xor(m, 16, 64));
        m = fmaxf(m, __shfl_xor(m, 32, 64));
        float sum = 0.f;
        #pragma unroll
        for (int rt = 0; rt < 13; ++rt) {
            st[rt][0] = __expf(st[rt][0] - m);
            st[rt][1] = __expf(st[rt][1] - m);
            st[rt][2] = __expf(st[rt][2] - m);
            st[rt][3] = __expf(st[rt][3] - m);
            sum += st[rt][0] + st[rt][1] + st[rt][2] + st[rt][3];
        }
        sum += __shfl_xor(sum, 16, 64);
        sum += __shfl_xor(sum, 32, 64);
        float inv = 1.0f / sum;

        unsigned int pk[13][2];
        #pragma unroll
        for (int rt = 0; rt < 13; ++rt) {
            pk[rt][0] = packbf(st[rt][0] * inv, st[rt][1] * inv);
            pk[rt][1] = packbf(st[rt][2] * inv, st[rt][3] * inv);
        }

        f32x4 ot[4];
        #pragma unroll
        for (int dt = 0; dt < 4; ++dt) ot[dt] = (f32x4){0.f, 0.f, 0.f, 0.f};
        #pragma unroll
        for (int c = 0; c < 7; ++c) {
            u32x4 fp;
            #pragma unroll
            for (int jp = 0; jp < 4; ++jp) {
                int jh = jp >> 1, rp = jp & 1;
                int srcb = ((((quad & 1) << 1) + jh) << 6) | (l16 << 2);
                int a = __builtin_amdgcn_ds_bpermute(srcb, (int)pk[2 * c][rp]);
                int b = (c < 6) ? __builtin_amdgcn_ds_bpermute(srcb, (int)pk[2 * c + 1][rp]) : 0;
                fp[jp] = (quad >> 1) ? (unsigned int)b : (unsigned int)a;
            }
            bf16x8 pB = __builtin_bit_cast(bf16x8, fp);
            #pragma unroll
            for (int dt = 0; dt < 4; ++dt) {
                bf16x8 vf = *(const bf16x8*)(Vt + (dt * 16 + l16) * VSTR + c * 32 + quad * 8);
                ot[dt] = __builtin_amdgcn_mfma_f32_16x16x32_bf16(vf, pB, ot[dt], 0, 0, 0);
            }
        }

        int token = qt * 16 + l16;
        if (token < S196) {
            bf16* op = O + ((long)bj * S196 + token) * CC + h * 64 + quad * 4;
            #pragma unroll
            for (int dt = 0; dt < 4; ++dt) {
                bf16x4 v;
                v[0] = f2bf(ot[dt][0]); v[1] = f2bf(ot[dt][1]);
                v[2] = f2bf(ot[dt][2]); v[3] = f2bf(ot[dt][3]);
                *(bf16x4*)(op + dt * 16) = v;
            }
        }
    }
}

// ---------------------------------------------------------------------------
extern "C" void kernel_launch(void* const* d_in, const int* in_sizes, int n_in,
                              void* d_out, int out_size, void* d_ws, size_t ws_size,
                              hipStream_t stream)
{
    const float* x_in  = (const float*)d_in[0];
    const float* Wq_d  = (const float*)d_in[1];
    const float* bq_d  = (const float*)d_in[2];
    const float* Wkv_a = (const float*)d_in[3];
    const float* bkv_a = (const float*)d_in[4];
    const float* Wq_a  = (const float*)d_in[5];
    const float* bq_a  = (const float*)d_in[6];
    const float* Wkv_d = (const float*)d_in[7];
    const float* bkv_d = (const float*)d_in[8];
    const float* Wp_d  = (const float*)d_in[9];
    const float* bp_d  = (const float*)d_in[10];
    const float* Wp_a  = (const float*)d_in[11];
    const float* bp_a  = (const float*)d_in[12];
    float* out = (float*)d_out;

    char* w = (char*)d_ws;
    auto alloc = [&](size_t elems) {
        bf16* p = (bf16*)w;
        w += ((elems * 2 + 255) / 256) * 256;
        return p;
    };
    bf16* biasAll = alloc(6144);
    bf16* WtQd  = alloc((size_t)768 * 768);
    bf16* WtACat= alloc((size_t)2304 * 768);   // [Wkv_a^T ; Wq_a^T]
    bf16* WtKd  = alloc((size_t)1536 * 768);
    bf16* WtPd  = alloc((size_t)768 * 768);
    bf16* WtPa  = alloc((size_t)768 * 768);
    bf16* xa    = alloc((size_t)M_ROWS * 768);
    bf16* xd    = alloc((size_t)M_ROWS * 768);
    bf16* Qb    = alloc((size_t)M_ROWS * 768);
    bf16* QKVa  = alloc((size_t)M_ROWS * 2304); // cols 0..1535 kv, 1536..2303 q_a
    bf16* Ob    = alloc((size_t)M_ROWS * 768);
    float* pool0 = (float*)w; w += ((size_t)M_ROWS * 4 + 255) / 256 * 256;

    dim3 blk(256);
    transpose_all<<<dim3(24, 48, 6), blk, 0, stream>>>(
        Wq_d, Wkv_a, Wq_a, Wkv_d, Wp_d, Wp_a,
        WtQd, WtACat, WtACat + (size_t)1536 * 768, WtKd, WtPd, WtPa);
    conv_bias<<<dim3(6), blk, 0, stream>>>(bq_d, bkv_a, bq_a, bkv_d, bp_d, bp_a, biasAll);

    long total_chunks = (long)BATCH * 16 * S196 * 96;
    int  rblocks = (int)((total_chunks + 255) / 256);
    reorder_split<<<rblocks, blk, 0, stream>>>(x_in, xa, xd);
    pool_ad<<<M_ROWS / 4, blk, 0, stream>>>(xa, xd, pool0);

    const bf16* Bq_d   = biasAll;
    const bf16* Bkva_qa= biasAll + 768;   // 2304-wide: bkv_a | bq_a
    const bf16* Bkv_d  = biasAll + 3072;
    const bf16* Bp_d   = biasAll + 4608;
    const bf16* Bp_a   = biasAll + 5376;

    // mTiles = 196 (M=25088/128); nTiles = N/256: 3 (768), 6 (1536), 9 (2304)
    // Phase 1: Qb = xd@Wq_d ; QKVa = xa@[Wkv_a|Wq_a]
    gemm_bt<0><<<196 * 3, blk, 0, stream>>>(xd, WtQd,  Bq_d,    nullptr, Qb,   768,  768, 196, 3);
    gemm_bt<0><<<196 * 9, blk, 0, stream>>>(xa, WtACat, Bkva_qa, nullptr, QKVa, 2304, 768, 196, 9);
    attn_mfma<<<dim3(12, 128), blk, 0, stream>>>(Qb, 768, QKVa, 2304, Ob);
    gemm_bt<1><<<196 * 3, blk, 0, stream>>>(Ob, WtPd, Bp_d, xd, xd, 768, 768, 196, 3);

    // Phase 2: kv_d overwrites QKVa cols 0..1535 (kv_a is dead after attn1)
    gemm_bt<0><<<196 * 6, blk, 0, stream>>>(xd, WtKd, Bkv_d, nullptr, QKVa, 2304, 768, 196, 6);
    attn_mfma<<<dim3(12, 128), blk, 0, stream>>>(QKVa + 1536, 2304, QKVa, 2304, Ob);
    gemm_bt<2><<<196 * 3, blk, 0, stream>>>(Ob, WtPa, Bp_a, xa, xa, 768, 768, 196, 3);

    out_final<<<M_ROWS / 4, blk, 0, stream>>>(xa, xd, pool0, out);
}